// Round 9
// baseline (533.560 us; speedup 1.0000x reference)
//
#include <hip/hip_runtime.h>

constexpr int kB  = 32;
constexpr int kNQ = 256;   // rows n
constexpr int kNT = 512;   // cols m
constexpr float kInf = 1e30f;
constexpr int kQTile = 32; // queries per cost block
constexpr int kSlots = 64; // LDS row-cache entries (64 x 2KB = 128KB), tag-per-lane max

// ---------------------------------------------------------------------------
// Kernel 1: final_cost [B, NQ, NT]. 512 thr/block, thread == target t.
// (proven passing, bit-identical math across all passing rounds)
// ---------------------------------------------------------------------------
__global__ __launch_bounds__(512)
void cost_kernel(const float* __restrict__ trans,
                 const float* __restrict__ qpos,
                 const float* __restrict__ rot,
                 const float* __restrict__ pose,
                 float* __restrict__ cost)
{
    __shared__ float sPose[kNT * 23];   // 47104 B

    const int b     = blockIdx.x;
    const int qBase = blockIdx.y * kQTile;
    const int tid   = threadIdx.x;      // target index t

    const float* pb = pose + (size_t)b * kNT * 23;
    for (int idx = tid; idx < kNT * 23; idx += 512) sPose[idx] = pb[idx];
    __syncthreads();

    float T[23];
    #pragma unroll
    for (int d = 0; d < 23; ++d) T[d] = sPose[tid * 23 + d];

    float s = 0.f;
    #pragma unroll
    for (int d = 0; d < 23; ++d) s += fabsf(T[d]);
    const bool valid = (s > 0.f);

    const float* tr = trans + ((size_t)b * kNQ + qBase) * 3;
    const float* qp = qpos  + ((size_t)b * kNQ + qBase) * 16;
    const float* rt = rot   + ((size_t)b * kNQ + qBase) * 4;
    float* cb = cost + ((size_t)b * kNQ + qBase) * kNT + tid;

    for (int q = 0; q < kQTile; ++q) {
        const float Q0 = tr[q * 3 + 0], Q1 = tr[q * 3 + 1], Q2 = tr[q * 3 + 2];
        float a = fabsf(Q0 - T[0]);
        a += fabsf(Q1 - T[1]);
        a += fabsf(Q2 - T[2]);
        float bsum = 0.f;
        #pragma unroll
        for (int d = 0; d < 16; ++d) bsum += fabsf(qp[q * 16 + d] - T[3 + d]);
        const float r0 = rt[q * 4 + 0], r1 = rt[q * 4 + 1];
        const float r2 = rt[q * 4 + 2], r3 = rt[q * 4 + 3];
        float dot = r0 * T[19] + r1 * T[20] + r2 * T[21] + r3 * T[22];
        float c = (a + bsum) + (1.0f - fabsf(dot));
        cb[(size_t)q * kNT] = valid ? c : kInf;
    }
}

// Wave64 min-reduction via DPP (rocPRIM pattern) over u32 keys.
__device__ __forceinline__ unsigned wave_min_u32(unsigned x) {
    unsigned t;
    t = (unsigned)__builtin_amdgcn_update_dpp((int)0xFFFFFFFF, (int)x, 0x111, 0xF, 0xF, false); x = t < x ? t : x; // row_shr:1
    t = (unsigned)__builtin_amdgcn_update_dpp((int)0xFFFFFFFF, (int)x, 0x112, 0xF, 0xF, false); x = t < x ? t : x; // row_shr:2
    t = (unsigned)__builtin_amdgcn_update_dpp((int)0xFFFFFFFF, (int)x, 0x114, 0xF, 0xF, false); x = t < x ? t : x; // row_shr:4
    t = (unsigned)__builtin_amdgcn_update_dpp((int)0xFFFFFFFF, (int)x, 0x118, 0xF, 0xF, false); x = t < x ? t : x; // row_shr:8
    t = (unsigned)__builtin_amdgcn_update_dpp((int)0xFFFFFFFF, (int)x, 0x142, 0xF, 0xF, false); x = t < x ? t : x; // row_bcast:15
    t = (unsigned)__builtin_amdgcn_update_dpp((int)0xFFFFFFFF, (int)x, 0x143, 0xF, 0xF, false); x = t < x ? t : x; // row_bcast:31
    return (unsigned)__builtin_amdgcn_readlane((int)x, 63);
}

// Order-preserving flip: float bits -> u32 keys (total order, handles negatives).
__device__ __forceinline__ unsigned fkey(float f) {
    unsigned s = __float_as_uint(f);
    return (s & 0x80000000u) ? ~s : (s | 0x80000000u);
}
__device__ __forceinline__ float funkey(unsigned k) {
    unsigned s = (k & 0x80000000u) ? (k & 0x7fffffffu) : ~k;
    return __uint_as_float(s);
}

// ---------------------------------------------------------------------------
// Kernel 2: JV LSAP — frozen numerics (v=0, u=row-min, greedy argmin match;
// wave-0 SAP with DPP u32 min + ballot lowest-lane tie-break + speculative
// row4col prefetch). R9 changes (all value-exact):
//  - Phase A row-min scan is wave-cooperative & coalesced (lane owns 8
//    contiguous cols; flip-key DPP min + ballot => exact lowest-col argmin,
//    bit-identical min value: fp min is order-invariant, no -0 in costs).
//  - LDS row cache stored SoA: cache[slot][c*64+lane] -> 8x ds_read_b32 /
//    ds_write_b32 at bank=lane%32 (2-way aliasing = free) instead of
//    4-way-conflicted ds_read_b128 (R8's 207k SQ_LDS_BANK_CONFLICT).
//  - 64 slots (tag-per-lane max), 128 KB.
// ---------------------------------------------------------------------------
__global__ __launch_bounds__(256)
void hungarian_kernel(const float* __restrict__ cost,
                      float* __restrict__ outInds,
                      float* __restrict__ outMask)
{
    __shared__ float rowCache[kSlots * kNT];   // 128 KB, SoA per slot
    __shared__ float u[kNQ];
    __shared__ int   col4row[kNQ];
    __shared__ int   row4col[kNT];
    __shared__ int   colBest[kNT];
    __shared__ int   pathL[kNT];
    __shared__ int   rowArg[kNQ];

    const int b   = blockIdx.x;
    const int tid = threadIdx.x;
    const float* __restrict__ C = cost + (size_t)b * kNQ * kNT;

    // ---- Phase A: row minima + argmin, wave-cooperative (4 waves x 64 rows) --
    {
        const int wv = tid >> 6, ln = tid & 63;
        for (int r = 0; r < 64; ++r) {
            const int row = wv * 64 + r;
            const float4* rp = (const float4*)(C + (size_t)row * kNT + ln * 8);
            const float4 a0 = rp[0], a1 = rp[1];
            const float cc[8] = {a0.x, a0.y, a0.z, a0.w, a1.x, a1.y, a1.z, a1.w};
            unsigned bv = 0xFFFFFFFFu; int bc = 0;
            #pragma unroll
            for (int c = 0; c < 8; ++c) {
                const unsigned k = fkey(cc[c]);
                if (k < bv) { bv = k; bc = c; }   // strict <: lowest slot on tie
            }
            const unsigned g = wave_min_u32(bv);
            const unsigned long long bal = __ballot(bv == g);
            const int wl  = (int)__ffsll(bal) - 1;           // lowest lane = lowest col
            const int jmn = __builtin_amdgcn_readlane(ln * 8 + bc, wl);
            if (ln == 0) { u[row] = funkey(g); rowArg[row] = jmn; }
        }
    }
    col4row[tid] = -1;
    row4col[tid] = -1;         row4col[tid + 256] = -1;
    colBest[tid] = 0x7fffffff; colBest[tid + 256] = 0x7fffffff;
    __syncthreads();
    atomicMin(&colBest[rowArg[tid]], tid);
    __syncthreads();
    {
        const int j = rowArg[tid];
        if (colBest[j] == tid) { col4row[tid] = j; row4col[j] = tid; }
    }
    __syncthreads();

    // ---- Phase C: augmenting searches, wave 0 only (wave-synchronous) ----
    if (tid < 64) {
        const int lane = tid;
        float vR[8];
        #pragma unroll
        for (int c = 0; c < 8; ++c) vR[c] = 0.f;

        int tagReg = -1;   // lane-indexed cache tag (slot == lane)
        int rr     = 0;    // wave-uniform round-robin fill pointer

        for (int cur = 0; cur < kNQ; ++cur) {
            if (col4row[cur] >= 0) continue;   // uniform branch

            float spcR[8]; int pathR[8];
            #pragma unroll
            for (int c = 0; c < 8; ++c) { spcR[c] = kInf; pathR[c] = -1; }
            unsigned scMask = 0;

            int   i      = cur;
            float minVal = 0.f;
            int   sink   = -1;

            for (int guard = 0; guard < kNT + 2 && sink < 0; ++guard) {
                const float ui = u[i];            // LDS read, overlaps row fetch
                float cc[8];
                const unsigned long long hm = __ballot(tagReg == i);
                if (hm != 0ull) {                 // cache hit (wave-uniform)
                    const int slot = (int)__ffsll(hm) - 1;
                    const float* lp = &rowCache[slot * kNT + lane];
                    #pragma unroll
                    for (int c = 0; c < 8; ++c) cc[c] = lp[c * 64]; // 8x b32, conflict-free
                } else {                          // miss: global (L2) load
                    const float4* rp = (const float4*)(C + (size_t)i * kNT + lane * 8);
                    const float4 p0 = rp[0], p1 = rp[1];
                    cc[0]=p0.x; cc[1]=p0.y; cc[2]=p0.z; cc[3]=p0.w;
                    cc[4]=p1.x; cc[5]=p1.y; cc[6]=p1.z; cc[7]=p1.w;
                    if (guard != 0) {             // don't cache one-shot cur rows
                        float* wp = &rowCache[rr * kNT + lane];
                        #pragma unroll
                        for (int c = 0; c < 8; ++c) wp[c * 64] = cc[c]; // conflict-free
                        if (lane == rr) tagReg = i;
                        rr = rr + 1; if (rr == kSlots) rr = 0;
                    }
                }
                #pragma unroll
                for (int c = 0; c < 8; ++c) {
                    if (!((scMask >> c) & 1u)) {
                        const float r = ((minVal + cc[c]) - ui) - vR[c];
                        if (r < spcR[c]) { spcR[c] = r; pathR[c] = i; }
                    }
                }

                // local argmin over 8 slots (u32 view, nonneg; strict < =>
                // lowest slot wins ties); swept slots masked to UINT_MAX
                unsigned sp[8];
                #pragma unroll
                for (int c = 0; c < 8; ++c)
                    sp[c] = ((scMask >> c) & 1u) ? 0xFFFFFFFFu
                                                 : __float_as_uint(spcR[c]);
                unsigned mA = sp[1] < sp[0] ? sp[1] : sp[0]; int aA = sp[1] < sp[0] ? 1 : 0;
                unsigned mB = sp[3] < sp[2] ? sp[3] : sp[2]; int aB = sp[3] < sp[2] ? 3 : 2;
                unsigned mC = sp[5] < sp[4] ? sp[5] : sp[4]; int aC = sp[5] < sp[4] ? 5 : 4;
                unsigned mD = sp[7] < sp[6] ? sp[7] : sp[6]; int aD = sp[7] < sp[6] ? 7 : 6;
                unsigned mAB = mB < mA ? mB : mA; int aAB = mB < mA ? aB : aA;
                unsigned mCD = mD < mC ? mD : mC; int aCD = mD < mC ? aD : aC;
                unsigned lvu = mCD < mAB ? mCD : mAB; int lc = mCD < mAB ? aCD : aAB;
                const int lix  = lane * 8 + lc;
                const int spec = row4col[lix];          // speculative owner prefetch

                const unsigned gmu = wave_min_u32(lvu); // hides the LDS read above
                const unsigned long long bal = __ballot(lvu == gmu);
                const int wl    = (int)__ffsll(bal) - 1;
                const int jstar = __builtin_amdgcn_readlane(lix, wl);
                const int own   = __builtin_amdgcn_readlane(spec, wl);
                minVal = __uint_as_float(gmu);

                if (wl == lane) scMask |= 1u << (jstar & 7);
                if (own < 0) sink = jstar;
                else         i    = own;
            }

            // ---- dual updates (pre-augment matching, per swept column) ----
            if (lane == 0) u[cur] += minVal;
            #pragma unroll
            for (int c = 0; c < 8; ++c) {
                if ((scMask >> c) & 1u) {
                    const int j = lane * 8 + c;
                    const int r = row4col[j];
                    const float d = minVal - spcR[c];
                    if (r >= 0) u[r] += d;   // owners distinct (matching invariant)
                    vR[c] -= d;
                    pathL[j] = pathR[c];
                }
            }
            __threadfence_block();

            // ---- augment along alternating path (lane 0) ----
            if (lane == 0 && sink >= 0) {
                int j = sink;
                while (true) {
                    const int pi = pathL[j];
                    row4col[j] = pi;
                    const int nj = col4row[pi];
                    col4row[pi] = j;
                    if (pi == cur) break;
                    j = nj;
                }
            }
            __threadfence_block();
        }
    }
    __syncthreads();

    outInds[(size_t)b * kNQ + tid] = (float)col4row[tid];
    outMask[(size_t)b * kNQ + tid] = 1.0f;
}

extern "C" void kernel_launch(void* const* d_in, const int* in_sizes, int n_in,
                              void* d_out, int out_size, void* d_ws, size_t ws_size,
                              hipStream_t stream) {
    const float* trans = (const float*)d_in[0];
    const float* qpos  = (const float*)d_in[1];
    const float* rot   = (const float*)d_in[2];
    const float* pose  = (const float*)d_in[3];

    float* out  = (float*)d_out;
    float* cost = out;
    float* inds = out + (size_t)kB * kNQ * kNT;
    float* mask = inds + (size_t)kB * kNQ;

    dim3 g1(kB, kNQ / kQTile);
    cost_kernel<<<g1, 512, 0, stream>>>(trans, qpos, rot, pose, cost);
    hungarian_kernel<<<kB, 256, 0, stream>>>(cost, inds, mask);
}

// Round 10
// 517.348 us; speedup vs baseline: 1.0313x; 1.0313x over previous
//
#include <hip/hip_runtime.h>

constexpr int kB  = 32;
constexpr int kNQ = 256;   // rows n
constexpr int kNT = 512;   // cols m
constexpr float kInf = 1e30f;
constexpr int kQTile = 32;    // queries per cost block
constexpr int kSlots = 56;    // LDS row-cache entries
constexpr int kStride = 544;  // 8 groups x (64 data + 4 pad) floats -> b128 bank-balanced

// ---------------------------------------------------------------------------
// Kernel 1: final_cost [B, NQ, NT]. 512 thr/block, thread == target t.
// (proven passing, bit-identical math across all passing rounds)
// ---------------------------------------------------------------------------
__global__ __launch_bounds__(512)
void cost_kernel(const float* __restrict__ trans,
                 const float* __restrict__ qpos,
                 const float* __restrict__ rot,
                 const float* __restrict__ pose,
                 float* __restrict__ cost)
{
    __shared__ float sPose[kNT * 23];   // 47104 B

    const int b     = blockIdx.x;
    const int qBase = blockIdx.y * kQTile;
    const int tid   = threadIdx.x;      // target index t

    const float* pb = pose + (size_t)b * kNT * 23;
    for (int idx = tid; idx < kNT * 23; idx += 512) sPose[idx] = pb[idx];
    __syncthreads();

    float T[23];
    #pragma unroll
    for (int d = 0; d < 23; ++d) T[d] = sPose[tid * 23 + d];

    float s = 0.f;
    #pragma unroll
    for (int d = 0; d < 23; ++d) s += fabsf(T[d]);
    const bool valid = (s > 0.f);

    const float* tr = trans + ((size_t)b * kNQ + qBase) * 3;
    const float* qp = qpos  + ((size_t)b * kNQ + qBase) * 16;
    const float* rt = rot   + ((size_t)b * kNQ + qBase) * 4;
    float* cb = cost + ((size_t)b * kNQ + qBase) * kNT + tid;

    for (int q = 0; q < kQTile; ++q) {
        const float Q0 = tr[q * 3 + 0], Q1 = tr[q * 3 + 1], Q2 = tr[q * 3 + 2];
        float a = fabsf(Q0 - T[0]);
        a += fabsf(Q1 - T[1]);
        a += fabsf(Q2 - T[2]);
        float bsum = 0.f;
        #pragma unroll
        for (int d = 0; d < 16; ++d) bsum += fabsf(qp[q * 16 + d] - T[3 + d]);
        const float r0 = rt[q * 4 + 0], r1 = rt[q * 4 + 1];
        const float r2 = rt[q * 4 + 2], r3 = rt[q * 4 + 3];
        float dot = r0 * T[19] + r1 * T[20] + r2 * T[21] + r3 * T[22];
        float c = (a + bsum) + (1.0f - fabsf(dot));
        cb[(size_t)q * kNT] = valid ? c : kInf;
    }
}

// Wave64 min-reduction via DPP (rocPRIM pattern). All inputs are non-negative
// float bit-patterns, so u32 order == f32 order. Result broadcast via lane 63.
__device__ __forceinline__ unsigned wave_min_u32(unsigned x) {
    unsigned t;
    t = (unsigned)__builtin_amdgcn_update_dpp((int)0xFFFFFFFF, (int)x, 0x111, 0xF, 0xF, false); x = t < x ? t : x; // row_shr:1
    t = (unsigned)__builtin_amdgcn_update_dpp((int)0xFFFFFFFF, (int)x, 0x112, 0xF, 0xF, false); x = t < x ? t : x; // row_shr:2
    t = (unsigned)__builtin_amdgcn_update_dpp((int)0xFFFFFFFF, (int)x, 0x114, 0xF, 0xF, false); x = t < x ? t : x; // row_shr:4
    t = (unsigned)__builtin_amdgcn_update_dpp((int)0xFFFFFFFF, (int)x, 0x118, 0xF, 0xF, false); x = t < x ? t : x; // row_shr:8
    t = (unsigned)__builtin_amdgcn_update_dpp((int)0xFFFFFFFF, (int)x, 0x142, 0xF, 0xF, false); x = t < x ? t : x; // row_bcast:15
    t = (unsigned)__builtin_amdgcn_update_dpp((int)0xFFFFFFFF, (int)x, 0x143, 0xF, 0xF, false); x = t < x ? t : x; // row_bcast:31
    return (unsigned)__builtin_amdgcn_readlane((int)x, 63);
}

// ---------------------------------------------------------------------------
// Kernel 2: JV LSAP — R8's PROVEN structure frozen (v=0, u=row-min, greedy
// argmin match; per-thread Phase A; wave-0 SAP with DPP u32 min + ballot
// lowest-lane tie-break + speculative row4col prefetch; 2x b128 AoS cache
// hit path). ONE layout change vs R8: cache rows padded (stride 544 = 8
// groups of 64 floats + 4-float pad), making both ds_read_b128 and
// ds_write_b128 perfectly bank-balanced (8 accesses/bank = floor).
// Value-exact: identical bits either path.
// ---------------------------------------------------------------------------
__global__ __launch_bounds__(256)
void hungarian_kernel(const float* __restrict__ cost,
                      float* __restrict__ outInds,
                      float* __restrict__ outMask)
{
    __shared__ float rowCache[kSlots * kStride];  // 121856 B
    __shared__ float u[kNQ];
    __shared__ int   col4row[kNQ];
    __shared__ int   row4col[kNT];
    __shared__ int   colBest[kNT];
    __shared__ int   pathL[kNT];
    __shared__ int   rowArg[kNQ];

    const int b   = blockIdx.x;
    const int tid = threadIdx.x;
    const float* __restrict__ C = cost + (size_t)b * kNQ * kNT;

    // ---- Phase A: row minima + greedy matching (thread t == row t) ----
    {
        const float4* Crow = (const float4*)(C + (size_t)tid * kNT);
        float bm = kInf; int barg = 0;
        #pragma unroll 4
        for (int j4 = 0; j4 < kNT / 4; ++j4) {
            float4 cc = Crow[j4];
            const int jb = j4 * 4;
            if (cc.x < bm) { bm = cc.x; barg = jb + 0; }
            if (cc.y < bm) { bm = cc.y; barg = jb + 1; }
            if (cc.z < bm) { bm = cc.z; barg = jb + 2; }
            if (cc.w < bm) { bm = cc.w; barg = jb + 3; }
        }
        u[tid]      = bm;   // feasible: C - u - 0 >= 0 exactly; matched slack == 0 exactly
        rowArg[tid] = barg;
        col4row[tid] = -1;
    }
    row4col[tid] = -1;         row4col[tid + 256] = -1;
    colBest[tid] = 0x7fffffff; colBest[tid + 256] = 0x7fffffff;
    __syncthreads();
    atomicMin(&colBest[rowArg[tid]], tid);
    __syncthreads();
    {
        const int j = rowArg[tid];
        if (colBest[j] == tid) { col4row[tid] = j; row4col[j] = tid; }
    }
    __syncthreads();

    // ---- Phase C: augmenting searches, wave 0 only (wave-synchronous) ----
    if (tid < 64) {
        const int lane = tid;
        // padded per-lane base: group (lane>>3) * 68 + (lane&7) * 8 floats
        const int laneOff = (lane >> 3) * 68 + (lane & 7) * 8;

        float vR[8];
        #pragma unroll
        for (int c = 0; c < 8; ++c) vR[c] = 0.f;

        int tagReg = -1;   // lane-indexed cache tag (slot == lane, lanes 0..kSlots-1)
        int rr     = 0;    // wave-uniform round-robin fill pointer

        for (int cur = 0; cur < kNQ; ++cur) {
            if (col4row[cur] >= 0) continue;   // uniform branch

            float spcR[8]; int pathR[8];
            #pragma unroll
            for (int c = 0; c < 8; ++c) { spcR[c] = kInf; pathR[c] = -1; }
            unsigned scMask = 0;

            int   i      = cur;
            float minVal = 0.f;
            int   sink   = -1;

            for (int guard = 0; guard < kNT + 2 && sink < 0; ++guard) {
                const float ui = u[i];            // LDS read, overlaps row fetch
                float4 p0, p1;
                const unsigned long long hm = __ballot(tagReg == i);
                if (hm != 0ull) {                 // cache hit (wave-uniform)
                    const int slot = (int)__ffsll(hm) - 1;
                    const float4* lp = (const float4*)&rowCache[slot * kStride + laneOff];
                    p0 = lp[0]; p1 = lp[1];       // bank-balanced b128 pair
                } else {                          // miss: global (L2) load
                    const float4* rp = (const float4*)(C + (size_t)i * kNT + lane * 8);
                    p0 = rp[0]; p1 = rp[1];
                    if (guard != 0) {             // don't cache one-shot cur rows
                        float4* wp = (float4*)&rowCache[rr * kStride + laneOff];
                        wp[0] = p0; wp[1] = p1;   // fire-and-forget, bank-balanced
                        if (lane == rr) tagReg = i;
                        rr = rr + 1; if (rr == kSlots) rr = 0;
                    }
                }
                const float cc[8] = {p0.x, p0.y, p0.z, p0.w, p1.x, p1.y, p1.z, p1.w};
                #pragma unroll
                for (int c = 0; c < 8; ++c) {
                    if (!((scMask >> c) & 1u)) {
                        const float r = ((minVal + cc[c]) - ui) - vR[c];
                        if (r < spcR[c]) { spcR[c] = r; pathR[c] = i; }
                    }
                }

                // local argmin over 8 slots (u32 view, nonneg; strict < =>
                // lowest slot wins ties); swept slots masked to UINT_MAX
                unsigned sp[8];
                #pragma unroll
                for (int c = 0; c < 8; ++c)
                    sp[c] = ((scMask >> c) & 1u) ? 0xFFFFFFFFu
                                                 : __float_as_uint(spcR[c]);
                unsigned mA = sp[1] < sp[0] ? sp[1] : sp[0]; int aA = sp[1] < sp[0] ? 1 : 0;
                unsigned mB = sp[3] < sp[2] ? sp[3] : sp[2]; int aB = sp[3] < sp[2] ? 3 : 2;
                unsigned mC = sp[5] < sp[4] ? sp[5] : sp[4]; int aC = sp[5] < sp[4] ? 5 : 4;
                unsigned mD = sp[7] < sp[6] ? sp[7] : sp[6]; int aD = sp[7] < sp[6] ? 7 : 6;
                unsigned mAB = mB < mA ? mB : mA; int aAB = mB < mA ? aB : aA;
                unsigned mCD = mD < mC ? mD : mC; int aCD = mD < mC ? aD : aC;
                unsigned lvu = mCD < mAB ? mCD : mAB; int lc = mCD < mAB ? aCD : aAB;
                const int lix  = lane * 8 + lc;
                const int spec = row4col[lix];          // speculative owner prefetch

                const unsigned gmu = wave_min_u32(lvu); // hides the LDS read above
                const unsigned long long bal = __ballot(lvu == gmu);
                const int wl    = (int)__ffsll(bal) - 1;
                const int jstar = __builtin_amdgcn_readlane(lix, wl);
                const int own   = __builtin_amdgcn_readlane(spec, wl);
                minVal = __uint_as_float(gmu);

                if (wl == lane) scMask |= 1u << (jstar & 7);
                if (own < 0) sink = jstar;
                else         i    = own;
            }

            // ---- dual updates (pre-augment matching, per swept column) ----
            if (lane == 0) u[cur] += minVal;
            #pragma unroll
            for (int c = 0; c < 8; ++c) {
                if ((scMask >> c) & 1u) {
                    const int j = lane * 8 + c;
                    const int r = row4col[j];
                    const float d = minVal - spcR[c];
                    if (r >= 0) u[r] += d;   // owners distinct (matching invariant)
                    vR[c] -= d;
                    pathL[j] = pathR[c];
                }
            }
            __threadfence_block();

            // ---- augment along alternating path (lane 0) ----
            if (lane == 0 && sink >= 0) {
                int j = sink;
                while (true) {
                    const int pi = pathL[j];
                    row4col[j] = pi;
                    const int nj = col4row[pi];
                    col4row[pi] = j;
                    if (pi == cur) break;
                    j = nj;
                }
            }
            __threadfence_block();
        }
    }
    __syncthreads();

    outInds[(size_t)b * kNQ + tid] = (float)col4row[tid];
    outMask[(size_t)b * kNQ + tid] = 1.0f;
}

extern "C" void kernel_launch(void* const* d_in, const int* in_sizes, int n_in,
                              void* d_out, int out_size, void* d_ws, size_t ws_size,
                              hipStream_t stream) {
    const float* trans = (const float*)d_in[0];
    const float* qpos  = (const float*)d_in[1];
    const float* rot   = (const float*)d_in[2];
    const float* pose  = (const float*)d_in[3];

    float* out  = (float*)d_out;
    float* cost = out;
    float* inds = out + (size_t)kB * kNQ * kNT;
    float* mask = inds + (size_t)kB * kNQ;

    dim3 g1(kB, kNQ / kQTile);
    cost_kernel<<<g1, 512, 0, stream>>>(trans, qpos, rot, pose, cost);
    hungarian_kernel<<<kB, 256, 0, stream>>>(cost, inds, mask);
}

// Round 11
// 432.257 us; speedup vs baseline: 1.2344x; 1.1969x over previous
//
#include <hip/hip_runtime.h>

constexpr int kB  = 32;
constexpr int kNQ = 256;   // rows n
constexpr int kNT = 512;   // cols m
constexpr float kInf = 1e30f;
constexpr int kQTile = 32;    // queries per cost block
constexpr int kSlots = 56;    // LDS row-cache entries
constexpr int kStride = 544;  // 8 groups x (64 data + 4 pad) floats

// ---------------------------------------------------------------------------
// Kernel 1: final_cost [B, NQ, NT]. 512 thr/block, thread == target t.
// (proven passing, bit-identical math across all passing rounds)
// ---------------------------------------------------------------------------
__global__ __launch_bounds__(512)
void cost_kernel(const float* __restrict__ trans,
                 const float* __restrict__ qpos,
                 const float* __restrict__ rot,
                 const float* __restrict__ pose,
                 float* __restrict__ cost)
{
    __shared__ float sPose[kNT * 23];   // 47104 B

    const int b     = blockIdx.x;
    const int qBase = blockIdx.y * kQTile;
    const int tid   = threadIdx.x;      // target index t

    const float* pb = pose + (size_t)b * kNT * 23;
    for (int idx = tid; idx < kNT * 23; idx += 512) sPose[idx] = pb[idx];
    __syncthreads();

    float T[23];
    #pragma unroll
    for (int d = 0; d < 23; ++d) T[d] = sPose[tid * 23 + d];

    float s = 0.f;
    #pragma unroll
    for (int d = 0; d < 23; ++d) s += fabsf(T[d]);
    const bool valid = (s > 0.f);

    const float* tr = trans + ((size_t)b * kNQ + qBase) * 3;
    const float* qp = qpos  + ((size_t)b * kNQ + qBase) * 16;
    const float* rt = rot   + ((size_t)b * kNQ + qBase) * 4;
    float* cb = cost + ((size_t)b * kNQ + qBase) * kNT + tid;

    for (int q = 0; q < kQTile; ++q) {
        const float Q0 = tr[q * 3 + 0], Q1 = tr[q * 3 + 1], Q2 = tr[q * 3 + 2];
        float a = fabsf(Q0 - T[0]);
        a += fabsf(Q1 - T[1]);
        a += fabsf(Q2 - T[2]);
        float bsum = 0.f;
        #pragma unroll
        for (int d = 0; d < 16; ++d) bsum += fabsf(qp[q * 16 + d] - T[3 + d]);
        const float r0 = rt[q * 4 + 0], r1 = rt[q * 4 + 1];
        const float r2 = rt[q * 4 + 2], r3 = rt[q * 4 + 3];
        float dot = r0 * T[19] + r1 * T[20] + r2 * T[21] + r3 * T[22];
        float c = (a + bsum) + (1.0f - fabsf(dot));
        cb[(size_t)q * kNT] = valid ? c : kInf;
    }
}

// Wave64 min-reduction via DPP (rocPRIM pattern). All inputs are non-negative
// float bit-patterns (incl +inf sentinel), so u32 order == f32 order.
__device__ __forceinline__ unsigned wave_min_u32(unsigned x) {
    unsigned t;
    t = (unsigned)__builtin_amdgcn_update_dpp((int)0xFFFFFFFF, (int)x, 0x111, 0xF, 0xF, false); x = t < x ? t : x; // row_shr:1
    t = (unsigned)__builtin_amdgcn_update_dpp((int)0xFFFFFFFF, (int)x, 0x112, 0xF, 0xF, false); x = t < x ? t : x; // row_shr:2
    t = (unsigned)__builtin_amdgcn_update_dpp((int)0xFFFFFFFF, (int)x, 0x114, 0xF, 0xF, false); x = t < x ? t : x; // row_shr:4
    t = (unsigned)__builtin_amdgcn_update_dpp((int)0xFFFFFFFF, (int)x, 0x118, 0xF, 0xF, false); x = t < x ? t : x; // row_shr:8
    t = (unsigned)__builtin_amdgcn_update_dpp((int)0xFFFFFFFF, (int)x, 0x142, 0xF, 0xF, false); x = t < x ? t : x; // row_bcast:15
    t = (unsigned)__builtin_amdgcn_update_dpp((int)0xFFFFFFFF, (int)x, 0x143, 0xF, 0xF, false); x = t < x ? t : x; // row_bcast:31
    return (unsigned)__builtin_amdgcn_readlane((int)x, 63);
}

// ---------------------------------------------------------------------------
// Kernel 2: JV LSAP — frozen numerics (v=0, u=row-min, greedy argmin match;
// wave-0 SAP, DPP u32 min + ballot lowest-lane tie-break + speculative
// row4col prefetch; R10's padded AoS row cache). R11 change (value-exact):
// UNMASKED packed relax + frozen-at-sweep state:
//   - relax has no scMask tests; spc/path of swept columns may keep updating,
//     but their sweep-time values are frozen in frzV/frzP (bit-identical to
//     what R10's masking preserved: swept spc == selected minVal).
//   - argmin masking via mskA[c] in {0,+inf} added to spc (packed adds);
//     +inf sentinel > any finite spc => identical selection to UINT_MAX.
//   - float2 ext-vector arithmetic lowers to v_pk_add_f32; per-element IEEE
//     ops and order unchanged.
// ---------------------------------------------------------------------------
__global__ __launch_bounds__(256)
void hungarian_kernel(const float* __restrict__ cost,
                      float* __restrict__ outInds,
                      float* __restrict__ outMask)
{
    __shared__ float rowCache[kSlots * kStride];  // 121856 B
    __shared__ float u[kNQ];
    __shared__ int   col4row[kNQ];
    __shared__ int   row4col[kNT];
    __shared__ int   colBest[kNT];
    __shared__ int   pathL[kNT];
    __shared__ int   rowArg[kNQ];

    const int b   = blockIdx.x;
    const int tid = threadIdx.x;
    const float* __restrict__ C = cost + (size_t)b * kNQ * kNT;

    // ---- Phase A: row minima + greedy matching (thread t == row t) ----
    {
        const float4* Crow = (const float4*)(C + (size_t)tid * kNT);
        float bm = kInf; int barg = 0;
        #pragma unroll 4
        for (int j4 = 0; j4 < kNT / 4; ++j4) {
            float4 cc = Crow[j4];
            const int jb = j4 * 4;
            if (cc.x < bm) { bm = cc.x; barg = jb + 0; }
            if (cc.y < bm) { bm = cc.y; barg = jb + 1; }
            if (cc.z < bm) { bm = cc.z; barg = jb + 2; }
            if (cc.w < bm) { bm = cc.w; barg = jb + 3; }
        }
        u[tid]      = bm;   // feasible: C - u - 0 >= 0 exactly; matched slack == 0 exactly
        rowArg[tid] = barg;
        col4row[tid] = -1;
    }
    row4col[tid] = -1;         row4col[tid + 256] = -1;
    colBest[tid] = 0x7fffffff; colBest[tid + 256] = 0x7fffffff;
    __syncthreads();
    atomicMin(&colBest[rowArg[tid]], tid);
    __syncthreads();
    {
        const int j = rowArg[tid];
        if (colBest[j] == tid) { col4row[tid] = j; row4col[j] = tid; }
    }
    __syncthreads();

    // ---- Phase C: augmenting searches, wave 0 only (wave-synchronous) ----
    if (tid < 64) {
        const int lane = tid;
        const int laneOff = (lane >> 3) * 68 + (lane & 7) * 8;
        typedef float v2f __attribute__((ext_vector_type(2)));

        float vR[8];
        #pragma unroll
        for (int c = 0; c < 8; ++c) vR[c] = 0.f;

        int tagReg = -1;   // lane-indexed cache tag (slot == lane)
        int rr     = 0;    // wave-uniform round-robin fill pointer

        for (int cur = 0; cur < kNQ; ++cur) {
            if (col4row[cur] >= 0) continue;   // uniform branch

            float spcR[8]; int pathR[8]; float mskA[8]; float frzV[8]; int frzP[8];
            #pragma unroll
            for (int c = 0; c < 8; ++c) {
                spcR[c] = kInf; pathR[c] = -1; mskA[c] = 0.f;
                frzV[c] = 0.f;  frzP[c] = -1;
            }
            unsigned scMask = 0;

            int   i      = cur;
            float minVal = 0.f;
            int   sink   = -1;

            for (int guard = 0; guard < kNT + 2 && sink < 0; ++guard) {
                const float ui = u[i];            // LDS read, overlaps row fetch
                float4 p0, p1;
                const unsigned long long hm = __ballot(tagReg == i);
                if (hm != 0ull) {                 // cache hit (wave-uniform)
                    const int slot = (int)__ffsll(hm) - 1;
                    const float4* lp = (const float4*)&rowCache[slot * kStride + laneOff];
                    p0 = lp[0]; p1 = lp[1];
                } else {                          // miss: global (L2) load
                    const float4* rp = (const float4*)(C + (size_t)i * kNT + lane * 8);
                    p0 = rp[0]; p1 = rp[1];
                    if (guard != 0) {             // don't cache one-shot cur rows
                        float4* wp = (float4*)&rowCache[rr * kStride + laneOff];
                        wp[0] = p0; wp[1] = p1;   // fire-and-forget
                        if (lane == rr) tagReg = i;
                        rr = rr + 1; if (rr == kSlots) rr = 0;
                    }
                }

                // ---- UNMASKED packed relax (value-exact op order) ----
                const v2f cc2[4] = { {p0.x, p0.y}, {p0.z, p0.w},
                                     {p1.x, p1.y}, {p1.z, p1.w} };
                const v2f mv2 = { minVal, minVal };
                const v2f ui2 = { ui, ui };
                float r8[8];
                #pragma unroll
                for (int p = 0; p < 4; ++p) {
                    const v2f vv = { vR[2*p], vR[2*p + 1] };
                    const v2f rp2 = ((mv2 + cc2[p]) - ui2) - vv;
                    r8[2*p] = rp2.x; r8[2*p + 1] = rp2.y;
                }
                #pragma unroll
                for (int c = 0; c < 8; ++c) {
                    const bool lt = r8[c] < spcR[c];
                    spcR[c]  = lt ? r8[c] : spcR[c];
                    pathR[c] = lt ? i : pathR[c];
                }

                // ---- masked local argmin: msk = spc + {0|+inf}, u32 tree ----
                float mskv[8];
                #pragma unroll
                for (int p = 0; p < 4; ++p) {
                    const v2f s2 = { spcR[2*p], spcR[2*p + 1] };
                    const v2f a2 = { mskA[2*p], mskA[2*p + 1] };
                    const v2f m2 = s2 + a2;
                    mskv[2*p] = m2.x; mskv[2*p + 1] = m2.y;
                }
                unsigned sp[8];
                #pragma unroll
                for (int c = 0; c < 8; ++c) sp[c] = __float_as_uint(mskv[c]);
                unsigned mA = sp[1] < sp[0] ? sp[1] : sp[0]; int aA = sp[1] < sp[0] ? 1 : 0;
                unsigned mB = sp[3] < sp[2] ? sp[3] : sp[2]; int aB = sp[3] < sp[2] ? 3 : 2;
                unsigned mC = sp[5] < sp[4] ? sp[5] : sp[4]; int aC = sp[5] < sp[4] ? 5 : 4;
                unsigned mD = sp[7] < sp[6] ? sp[7] : sp[6]; int aD = sp[7] < sp[6] ? 7 : 6;
                unsigned mAB = mB < mA ? mB : mA; int aAB = mB < mA ? aB : aA;
                unsigned mCD = mD < mC ? mD : mC; int aCD = mD < mC ? aD : aC;
                unsigned lvu = mCD < mAB ? mCD : mAB; int lc = mCD < mAB ? aCD : aAB;
                const int lix  = lane * 8 + lc;
                const int spec = row4col[lix];          // speculative owner prefetch

                const unsigned gmu = wave_min_u32(lvu); // hides the LDS read above
                const unsigned long long bal = __ballot(lvu == gmu);
                const int wl    = (int)__ffsll(bal) - 1;
                const int jstar = __builtin_amdgcn_readlane(lix, wl);
                const int own   = __builtin_amdgcn_readlane(spec, wl);
                minVal = __uint_as_float(gmu);

                if (own < 0) sink = jstar;
                else         i    = own;

                if (wl == lane) {                 // freeze sweep-time state
                    const int lcw = jstar & 7;
                    scMask |= 1u << lcw;
                    #pragma unroll
                    for (int c = 0; c < 8; ++c) {
                        if (c == lcw) {
                            mskA[c] = __builtin_inff();
                            frzV[c] = minVal;     // == spcR[c] at sweep time
                            frzP[c] = pathR[c];
                        }
                    }
                }
            }

            // ---- dual updates (sweep-time values, per swept column) ----
            if (lane == 0) u[cur] += minVal;
            #pragma unroll
            for (int c = 0; c < 8; ++c) {
                if ((scMask >> c) & 1u) {
                    const int j = lane * 8 + c;
                    const int r = row4col[j];
                    const float d = minVal - frzV[c];
                    if (r >= 0) u[r] += d;   // owners distinct (matching invariant)
                    vR[c] -= d;
                    pathL[j] = frzP[c];
                }
            }
            __threadfence_block();

            // ---- augment along alternating path (lane 0) ----
            if (lane == 0 && sink >= 0) {
                int j = sink;
                while (true) {
                    const int pi = pathL[j];
                    row4col[j] = pi;
                    const int nj = col4row[pi];
                    col4row[pi] = j;
                    if (pi == cur) break;
                    j = nj;
                }
            }
            __threadfence_block();
        }
    }
    __syncthreads();

    outInds[(size_t)b * kNQ + tid] = (float)col4row[tid];
    outMask[(size_t)b * kNQ + tid] = 1.0f;
}

extern "C" void kernel_launch(void* const* d_in, const int* in_sizes, int n_in,
                              void* d_out, int out_size, void* d_ws, size_t ws_size,
                              hipStream_t stream) {
    const float* trans = (const float*)d_in[0];
    const float* qpos  = (const float*)d_in[1];
    const float* rot   = (const float*)d_in[2];
    const float* pose  = (const float*)d_in[3];

    float* out  = (float*)d_out;
    float* cost = out;
    float* inds = out + (size_t)kB * kNQ * kNT;
    float* mask = inds + (size_t)kB * kNQ;

    dim3 g1(kB, kNQ / kQTile);
    cost_kernel<<<g1, 512, 0, stream>>>(trans, qpos, rot, pose, cost);
    hungarian_kernel<<<kB, 256, 0, stream>>>(cost, inds, mask);
}